// Round 1
// baseline (1611.395 us; speedup 1.0000x reference)
//
#include <hip/hip_runtime.h>
#include <math.h>

#define N_SAMP 512
#define C_IN   12
#define L_IN   8192
#define PER    5
#define NDIL   6
#define NFILT  30   // NDIL * PER
#define NFEAT  180  // 3 * NFILT * 2 / ... (3 ks * 6 dil * 5 filt * 2)

// ---------------------------------------------------------------------------
// Kernel 1: dilated conv + PPV/max for one kernel-size, one sample per block.
// Grid: 512 blocks (one per sample). 256 threads. Writes raw features into
// d_out at [n*180 + ks_off + j*10 + p*2 + {0,1}].
// ---------------------------------------------------------------------------
template <int K>
__global__ __launch_bounds__(256, 2)
void rocket_conv(const float* __restrict__ x,
                 const float* __restrict__ W,
                 const float* __restrict__ b,
                 float* __restrict__ out,
                 int ks_off)
{
    constexpr int HALF = (K - 1) / 2;
    constexpr int HALO = HALF * 32;      // max dilation = 32
    constexpr int TL   = 1024;           // L tile
    constexpr int LW   = TL + 2 * HALO;  // LDS row width

    __shared__ float xs[C_IN][LW];
    __shared__ float redc[4][NFILT];
    __shared__ float redm[4][NFILT];

    const int n   = blockIdx.x;
    const int tid = threadIdx.x;
    const float* __restrict__ xrow = x + (size_t)n * C_IN * L_IN;

    float cnt[NFILT];
    float mx[NFILT];
#pragma unroll
    for (int g = 0; g < NFILT; ++g) { cnt[g] = 0.0f; mx[g] = -INFINITY; }

#pragma unroll 1
    for (int t0 = 0; t0 < L_IN; t0 += TL) {
        __syncthreads();
        // ---- stage x tile (+halo, zero-padded) into LDS ----
#pragma unroll 1
        for (int idx = tid; idx < C_IN * LW; idx += 256) {
            int c   = idx / LW;
            int off = idx - c * LW;
            int g   = t0 - HALO + off;
            xs[c][off] = (g >= 0 && g < L_IN) ? xrow[c * L_IN + g] : 0.0f;
        }
        __syncthreads();

        // ---- compute: 6 dilations (compile-time), 12 channels (rolled) ----
#pragma unroll
        for (int j = 0; j < NDIL; ++j) {
            const int d = 1 << j;
            float acc[4][PER];
#pragma unroll
            for (int p = 0; p < 4; ++p)
#pragma unroll
                for (int f = 0; f < PER; ++f)
                    acc[p][f] = b[j * PER + f];

#pragma unroll 1
            for (int c = 0; c < C_IN; ++c) {
                // wave-uniform weight loads (scalar-cached)
                float w[K][PER];
#pragma unroll
                for (int k = 0; k < K; ++k)
#pragma unroll
                    for (int f = 0; f < PER; ++f)
                        w[k][f] = W[((j * PER + f) * C_IN + c) * K + k];

#pragma unroll
                for (int p = 0; p < 4; ++p) {
                    const int li = HALO + tid + p * 256;
#pragma unroll
                    for (int k = 0; k < K; ++k) {
                        float xv = xs[c][li + (k - HALF) * d];
#pragma unroll
                        for (int f = 0; f < PER; ++f)
                            acc[p][f] = fmaf(w[k][f], xv, acc[p][f]);
                    }
                }
            }

#pragma unroll
            for (int p = 0; p < 4; ++p)
#pragma unroll
                for (int f = 0; f < PER; ++f) {
                    cnt[j * PER + f] += (acc[p][f] > 0.0f) ? 1.0f : 0.0f;
                    mx[j * PER + f]   = fmaxf(mx[j * PER + f], acc[p][f]);
                }
        }
    }

    // ---- block reduction: 256 threads -> 30 (cnt sum, max) ----
    const int lane = tid & 63;
    const int wv   = tid >> 6;
#pragma unroll 1
    for (int g = 0; g < NFILT; ++g) {
        float c = cnt[g], m = mx[g];
#pragma unroll
        for (int off = 32; off; off >>= 1) {
            c += __shfl_xor(c, off);
            m  = fmaxf(m, __shfl_xor(m, off));
        }
        if (lane == 0) { redc[wv][g] = c; redm[wv][g] = m; }
    }
    __syncthreads();

    if (tid < NFILT) {
        float c = 0.0f, m = -INFINITY;
#pragma unroll
        for (int w = 0; w < 4; ++w) {
            c += redc[w][tid];
            m  = fmaxf(m, redm[w][tid]);
        }
        const int j = tid / PER;
        const int p = tid - j * PER;
        const int base = n * NFEAT + ks_off + j * (2 * PER) + p * 2;
        out[base]     = c * (1.0f / (float)L_IN);  // PPV
        out[base + 1] = m;                          // max
    }
}

// ---------------------------------------------------------------------------
// Kernel 2: in-place per-feature batch normalization.
// Grid: 180 blocks (one per feature column), 512 threads (one per sample).
// ---------------------------------------------------------------------------
__global__ __launch_bounds__(512)
void rocket_norm(float* __restrict__ out)
{
    const int i = blockIdx.x;    // feature
    const int t = threadIdx.x;   // sample

    const float v = out[t * NFEAT + i];
    float s  = v;
    float sq = v * v;
#pragma unroll
    for (int off = 32; off; off >>= 1) {
        s  += __shfl_xor(s, off);
        sq += __shfl_xor(sq, off);
    }

    __shared__ float ss[8], sqq[8];
    const int lane = t & 63;
    const int wv   = t >> 6;
    if (lane == 0) { ss[wv] = s; sqq[wv] = sq; }
    __syncthreads();
    if (t == 0) {
        float S = 0.0f, Q = 0.0f;
#pragma unroll
        for (int w = 0; w < 8; ++w) { S += ss[w]; Q += sqq[w]; }
        ss[0] = S; sqq[0] = Q;
    }
    __syncthreads();

    const float mean = ss[0] * (1.0f / (float)N_SAMP);
    const float var  = sqq[0] * (1.0f / (float)N_SAMP) - mean * mean;
    out[t * NFEAT + i] = (v - mean) / sqrtf(var + 1e-5f);
}

// ---------------------------------------------------------------------------
extern "C" void kernel_launch(void* const* d_in, const int* in_sizes, int n_in,
                              void* d_out, int out_size, void* d_ws, size_t ws_size,
                              hipStream_t stream)
{
    const float* x   = (const float*)d_in[0];
    const float* W7  = (const float*)d_in[1];
    const float* b7  = (const float*)d_in[2];
    const float* W9  = (const float*)d_in[3];
    const float* b9  = (const float*)d_in[4];
    const float* W11 = (const float*)d_in[5];
    const float* b11 = (const float*)d_in[6];
    float* out = (float*)d_out;

    rocket_conv<7><<<N_SAMP, 256, 0, stream>>>(x, W7,  b7,  out, 0);
    rocket_conv<9><<<N_SAMP, 256, 0, stream>>>(x, W9,  b9,  out, 60);
    rocket_conv<11><<<N_SAMP, 256, 0, stream>>>(x, W11, b11, out, 120);
    rocket_norm<<<NFEAT, 512, 0, stream>>>(out);
}

// Round 2
// 1525.589 us; speedup vs baseline: 1.0562x; 1.0562x over previous
//
#include <hip/hip_runtime.h>
#include <math.h>

#define N_SAMP 512
#define C_IN   12
#define L_IN   8192
#define PER    5
#define NDIL   6
#define NFILT  30   // NDIL * PER
#define NFEAT  180  // 3 ks * 30 filters * 2 stats
#define NCHUNK 4
#define CHUNK  (L_IN / NCHUNK)   // 2048
#define EPSV   1e-5f

// ---------------------------------------------------------------------------
// Kernel 1: dilated conv + partial PPV/max for one kernel-size.
// Grid: (NCHUNK, N_SAMP) blocks, 256 threads. One (sample, L-chunk) per block.
// Writes raw partial (count, max) per filter into ws at
//   ws[(((ks*N + n)*NCHUNK + ch)*NFILT + g)*2 + {0,1}]
// ---------------------------------------------------------------------------
template <int K>
__global__ __launch_bounds__(256, 4)
void rocket_conv(const float* __restrict__ x,
                 const float* __restrict__ W,
                 const float* __restrict__ b,
                 float* __restrict__ ws,
                 int ks_idx)
{
    constexpr int HALF = (K - 1) / 2;
    constexpr int HALO = HALF * 32;      // max dilation = 32
    constexpr int TL   = 512;            // L tile
    constexpr int LW   = TL + 2 * HALO;  // LDS row width

    __shared__ float xs[C_IN][LW];       // <= 39936 B (K=11) -> 4 blocks/CU

    const int ch  = blockIdx.x;
    const int n   = blockIdx.y;
    const int tid = threadIdx.x;
    const float* __restrict__ xrow = x + (size_t)n * C_IN * L_IN;

    float cnt[NFILT];
    float mx[NFILT];
#pragma unroll
    for (int g = 0; g < NFILT; ++g) { cnt[g] = 0.0f; mx[g] = -INFINITY; }

    const int c0 = ch * CHUNK;
#pragma unroll 1
    for (int t0 = c0; t0 < c0 + CHUNK; t0 += TL) {
        __syncthreads();
        // ---- stage x tile (+halo, zero-padded at sequence ends) ----
#pragma unroll 1
        for (int idx = tid; idx < C_IN * LW; idx += 256) {
            int c   = idx / LW;
            int off = idx - c * LW;
            int g   = t0 - HALO + off;
            xs[c][off] = (g >= 0 && g < L_IN) ? xrow[c * L_IN + g] : 0.0f;
        }
        __syncthreads();

        // ---- compute: 6 dilations (compile-time) x 12 channels ----
#pragma unroll
        for (int j = 0; j < NDIL; ++j) {
            const int d = 1 << j;
            float acc[2][PER];
#pragma unroll
            for (int p = 0; p < 2; ++p)
#pragma unroll
                for (int f = 0; f < PER; ++f)
                    acc[p][f] = b[j * PER + f];

#pragma unroll 1
            for (int c = 0; c < C_IN; ++c) {
                // wave-uniform weight loads (scalar path)
                float w[K][PER];
#pragma unroll
                for (int k = 0; k < K; ++k)
#pragma unroll
                    for (int f = 0; f < PER; ++f)
                        w[k][f] = W[((j * PER + f) * C_IN + c) * K + k];

#pragma unroll
                for (int p = 0; p < 2; ++p) {
                    const int li = HALO + tid + p * 256;
#pragma unroll
                    for (int k = 0; k < K; ++k) {
                        float xv = xs[c][li + (k - HALF) * d];
#pragma unroll
                        for (int f = 0; f < PER; ++f)
                            acc[p][f] = fmaf(w[k][f], xv, acc[p][f]);
                    }
                }
            }

#pragma unroll
            for (int p = 0; p < 2; ++p)
#pragma unroll
                for (int f = 0; f < PER; ++f) {
                    cnt[j * PER + f] += (acc[p][f] > 0.0f) ? 1.0f : 0.0f;
                    mx[j * PER + f]   = fmaxf(mx[j * PER + f], acc[p][f]);
                }
        }
    }

    // ---- block reduction: 256 threads -> 30 (cnt sum, max) ----
    __syncthreads();                       // xs no longer read; alias it
    float* redc = &xs[0][0];               // [4][NFILT]
    float* redm = &xs[0][0] + 4 * NFILT;   // [4][NFILT]

    const int lane = tid & 63;
    const int wv   = tid >> 6;
#pragma unroll 1
    for (int g = 0; g < NFILT; ++g) {
        float c = cnt[g], m = mx[g];
#pragma unroll
        for (int off = 32; off; off >>= 1) {
            c += __shfl_xor(c, off);
            m  = fmaxf(m, __shfl_xor(m, off));
        }
        if (lane == 0) { redc[wv * NFILT + g] = c; redm[wv * NFILT + g] = m; }
    }
    __syncthreads();

    if (tid < NFILT) {
        float c = 0.0f, m = -INFINITY;
#pragma unroll
        for (int w = 0; w < 4; ++w) {
            c += redc[w * NFILT + tid];
            m  = fmaxf(m, redm[w * NFILT + tid]);
        }
        const size_t base =
            ((((size_t)ks_idx * N_SAMP + n) * NCHUNK + ch) * NFILT + tid) * 2;
        ws[base]     = c;   // raw positive count for this chunk
        ws[base + 1] = m;   // chunk max
    }
}

// ---------------------------------------------------------------------------
// Kernel 2: reduce chunks -> feature value, then per-feature batch norm.
// Grid: 180 blocks (one per feature), 512 threads (one per sample).
// ---------------------------------------------------------------------------
__global__ __launch_bounds__(512)
void rocket_finish(const float* __restrict__ ws, float* __restrict__ out)
{
    const int i = blockIdx.x;    // feature index 0..179
    const int t = threadIdx.x;   // sample

    const int ks = i / 60;
    const int r  = i % 60;       // j*10 + p*2 + m
    const int g  = r >> 1;       // j*5 + p
    const int m  = r & 1;        // 0 = ppv, 1 = max

    const size_t base =
        ((((size_t)ks * N_SAMP + t) * NCHUNK) * NFILT + g) * 2 + m;

    float v;
    if (m) {
        v = -INFINITY;
#pragma unroll
        for (int c = 0; c < NCHUNK; ++c)
            v = fmaxf(v, ws[base + (size_t)c * NFILT * 2]);
    } else {
        v = 0.0f;
#pragma unroll
        for (int c = 0; c < NCHUNK; ++c)
            v += ws[base + (size_t)c * NFILT * 2];
        v *= (1.0f / (float)L_IN);
    }

    // ---- mean / var over 512 samples ----
    float s  = v;
    float sq = v * v;
#pragma unroll
    for (int off = 32; off; off >>= 1) {
        s  += __shfl_xor(s, off);
        sq += __shfl_xor(sq, off);
    }

    __shared__ float ss[8], sqq[8];
    const int lane = t & 63;
    const int wv   = t >> 6;
    if (lane == 0) { ss[wv] = s; sqq[wv] = sq; }
    __syncthreads();
    if (t == 0) {
        float S = 0.0f, Q = 0.0f;
#pragma unroll
        for (int w = 0; w < 8; ++w) { S += ss[w]; Q += sqq[w]; }
        ss[0] = S; sqq[0] = Q;
    }
    __syncthreads();

    const float mean = ss[0] * (1.0f / (float)N_SAMP);
    const float var  = sqq[0] * (1.0f / (float)N_SAMP) - mean * mean;
    out[t * NFEAT + i] = (v - mean) / sqrtf(var + EPSV);
}

// ---------------------------------------------------------------------------
extern "C" void kernel_launch(void* const* d_in, const int* in_sizes, int n_in,
                              void* d_out, int out_size, void* d_ws, size_t ws_size,
                              hipStream_t stream)
{
    const float* x   = (const float*)d_in[0];
    const float* W7  = (const float*)d_in[1];
    const float* b7  = (const float*)d_in[2];
    const float* W9  = (const float*)d_in[3];
    const float* b9  = (const float*)d_in[4];
    const float* W11 = (const float*)d_in[5];
    const float* b11 = (const float*)d_in[6];
    float* out = (float*)d_out;
    float* ws  = (float*)d_ws;   // needs 3*512*4*30*2*4 B = 1.47 MB

    dim3 grid(NCHUNK, N_SAMP);
    rocket_conv<7><<<grid, 256, 0, stream>>>(x, W7,  b7,  ws, 0);
    rocket_conv<9><<<grid, 256, 0, stream>>>(x, W9,  b9,  ws, 1);
    rocket_conv<11><<<grid, 256, 0, stream>>>(x, W11, b11, ws, 2);
    rocket_finish<<<NFEAT, 512, 0, stream>>>(ws, out);
}

// Round 3
// 1372.153 us; speedup vs baseline: 1.1744x; 1.1118x over previous
//
#include <hip/hip_runtime.h>
#include <math.h>

#define N_SAMP 512
#define C_IN   12
#define L_IN   8192
#define PER    5
#define NFILT  30   // 6 dilations * 5 filters
#define NFEAT  180  // 3 ks * 30 filters * 2 stats
#define NCHUNK 4
#define CHUNK  (L_IN / NCHUNK)   // 2048
#define TL     512               // positions per tile
#define EPSV   1e-5f

// ---------------------------------------------------------------------------
// Kernel 1: dilated conv + partial PPV/max for one kernel-size and one
// dilation GROUP (NDG dilations starting at index J0; DMAX = largest).
// Grid: (NCHUNK, N_SAMP), 256 threads. Each thread: 2 adjacent positions.
// Per-thread state: cnt[15]+mx[15]+acc[10] ~= 45 VGPRs -> no spills.
// ---------------------------------------------------------------------------
template <int K, int J0, int NDG, int DMAX>
__global__ __launch_bounds__(256, 4)
void rocket_conv(const float* __restrict__ x,
                 const float* __restrict__ W,
                 const float* __restrict__ b,
                 float* __restrict__ ws,
                 int ks_idx)
{
    constexpr int HALF = (K - 1) / 2;
    constexpr int HALO = HALF * DMAX;
    constexpr int LW   = TL + 2 * HALO;
    constexpr int NG   = NDG * PER;      // filters handled by this block (15)

    __shared__ float xs[C_IN][LW];
    __shared__ float redc[4][NG];
    __shared__ float redm[4][NG];

    const int ch  = blockIdx.x;
    const int n   = blockIdx.y;
    const int tid = threadIdx.x;
    const float* __restrict__ xrow = x + (size_t)n * C_IN * L_IN;

    float cnt[NG], mx[NG];
#pragma unroll
    for (int g = 0; g < NG; ++g) { cnt[g] = 0.0f; mx[g] = -INFINITY; }

    const int c0 = ch * CHUNK;
#pragma unroll 1
    for (int t0 = c0; t0 < c0 + CHUNK; t0 += TL) {
        __syncthreads();
        // ---- stage x tile (+halo, zero-padded at sequence ends) ----
#pragma unroll 1
        for (int c = 0; c < C_IN; ++c) {
#pragma unroll 1
            for (int off = tid; off < LW; off += 256) {
                int g = t0 - HALO + off;
                xs[c][off] = ((unsigned)g < (unsigned)L_IN) ? xrow[c * L_IN + g]
                                                            : 0.0f;
            }
        }
        __syncthreads();

        const int li = HALO + 2 * tid;   // first of 2 adjacent positions

#pragma unroll
        for (int jj = 0; jj < NDG; ++jj) {
            const int j = J0 + jj;       // global dilation index
            const int d = 1 << j;

            float a0[PER], a1[PER];
#pragma unroll
            for (int f = 0; f < PER; ++f) {
                float bb = b[j * PER + f];
                a0[f] = bb; a1[f] = bb;
            }

#pragma unroll 1
            for (int c = 0; c < C_IN; ++c) {
#pragma unroll
                for (int k = 0; k < K; ++k) {
                    const float* px = &xs[c][li + (k - HALF) * d];
                    const float x0 = px[0];
                    const float x1 = px[1];
#pragma unroll
                    for (int f = 0; f < PER; ++f) {
                        // wave-uniform weight -> scalar load, no VGPR cost
                        const float wv = W[((j * PER + f) * C_IN + c) * K + k];
                        a0[f] = fmaf(wv, x0, a0[f]);
                        a1[f] = fmaf(wv, x1, a1[f]);
                    }
                }
            }

#pragma unroll
            for (int f = 0; f < PER; ++f) {
                const int g = jj * PER + f;
                cnt[g] += ((a0[f] > 0.0f) ? 1.0f : 0.0f)
                        + ((a1[f] > 0.0f) ? 1.0f : 0.0f);
                mx[g]   = fmaxf(mx[g], fmaxf(a0[f], a1[f]));
            }
        }
    }

    // ---- block reduction: 256 threads -> NG (cnt sum, max) ----
    const int lane = tid & 63;
    const int wv   = tid >> 6;
#pragma unroll
    for (int g = 0; g < NG; ++g) {       // fully unrolled: static indices only
        float c = cnt[g], m = mx[g];
#pragma unroll
        for (int off = 32; off; off >>= 1) {
            c += __shfl_xor(c, off);
            m  = fmaxf(m, __shfl_xor(m, off));
        }
        if (lane == 0) { redc[wv][g] = c; redm[wv][g] = m; }
    }
    __syncthreads();

    if (tid < NG) {
        float c = 0.0f, m = -INFINITY;
#pragma unroll
        for (int w = 0; w < 4; ++w) {
            c += redc[w][tid];
            m  = fmaxf(m, redm[w][tid]);
        }
        const int g_global = J0 * PER + tid;   // 0..29 within this ks
        const size_t base =
            ((((size_t)ks_idx * N_SAMP + n) * NCHUNK + ch) * NFILT + g_global) * 2;
        ws[base]     = c;   // raw positive count for this chunk
        ws[base + 1] = m;   // chunk max
    }
}

// ---------------------------------------------------------------------------
// Kernel 2: reduce chunks -> feature value, then per-feature batch norm.
// Grid: 180 blocks (one per feature), 512 threads (one per sample).
// ---------------------------------------------------------------------------
__global__ __launch_bounds__(512)
void rocket_finish(const float* __restrict__ ws, float* __restrict__ out)
{
    const int i = blockIdx.x;    // feature index 0..179
    const int t = threadIdx.x;   // sample

    const int ks = i / 60;
    const int r  = i % 60;       // j*10 + f*2 + m
    const int g  = r >> 1;       // j*5 + f
    const int m  = r & 1;        // 0 = ppv, 1 = max

    const size_t base =
        ((((size_t)ks * N_SAMP + t) * NCHUNK) * NFILT + g) * 2 + m;

    float v;
    if (m) {
        v = -INFINITY;
#pragma unroll
        for (int c = 0; c < NCHUNK; ++c)
            v = fmaxf(v, ws[base + (size_t)c * NFILT * 2]);
    } else {
        v = 0.0f;
#pragma unroll
        for (int c = 0; c < NCHUNK; ++c)
            v += ws[base + (size_t)c * NFILT * 2];
        v *= (1.0f / (float)L_IN);
    }

    // ---- mean / var over 512 samples ----
    float s  = v;
    float sq = v * v;
#pragma unroll
    for (int off = 32; off; off >>= 1) {
        s  += __shfl_xor(s, off);
        sq += __shfl_xor(sq, off);
    }

    __shared__ float ss[8], sqq[8];
    const int lane = t & 63;
    const int wv   = t >> 6;
    if (lane == 0) { ss[wv] = s; sqq[wv] = sq; }
    __syncthreads();
    if (t == 0) {
        float S = 0.0f, Q = 0.0f;
#pragma unroll
        for (int w = 0; w < 8; ++w) { S += ss[w]; Q += sqq[w]; }
        ss[0] = S; sqq[0] = Q;
    }
    __syncthreads();

    const float mean = ss[0] * (1.0f / (float)N_SAMP);
    const float var  = sqq[0] * (1.0f / (float)N_SAMP) - mean * mean;
    out[t * NFEAT + i] = (v - mean) / sqrtf(var + EPSV);
}

// ---------------------------------------------------------------------------
extern "C" void kernel_launch(void* const* d_in, const int* in_sizes, int n_in,
                              void* d_out, int out_size, void* d_ws, size_t ws_size,
                              hipStream_t stream)
{
    const float* x   = (const float*)d_in[0];
    const float* W7  = (const float*)d_in[1];
    const float* b7  = (const float*)d_in[2];
    const float* W9  = (const float*)d_in[3];
    const float* b9  = (const float*)d_in[4];
    const float* W11 = (const float*)d_in[5];
    const float* b11 = (const float*)d_in[6];
    float* out = (float*)d_out;
    float* ws  = (float*)d_ws;   // needs 3*512*4*30*2*4 B = 1.47 MB

    dim3 grid(NCHUNK, N_SAMP);
    // dilation groups: {1,2,4} (J0=0, DMAX=4) and {8,16,32} (J0=3, DMAX=32)
    rocket_conv< 7, 0, 3,  4><<<grid, 256, 0, stream>>>(x, W7,  b7,  ws, 0);
    rocket_conv< 7, 3, 3, 32><<<grid, 256, 0, stream>>>(x, W7,  b7,  ws, 0);
    rocket_conv< 9, 0, 3,  4><<<grid, 256, 0, stream>>>(x, W9,  b9,  ws, 1);
    rocket_conv< 9, 3, 3, 32><<<grid, 256, 0, stream>>>(x, W9,  b9,  ws, 1);
    rocket_conv<11, 0, 3,  4><<<grid, 256, 0, stream>>>(x, W11, b11, ws, 2);
    rocket_conv<11, 3, 3, 32><<<grid, 256, 0, stream>>>(x, W11, b11, ws, 2);

    rocket_finish<<<NFEAT, 512, 0, stream>>>(ws, out);
}

// Round 4
// 1319.785 us; speedup vs baseline: 1.2210x; 1.0397x over previous
//
#include <hip/hip_runtime.h>
#include <math.h>

#define N_SAMP 512
#define C_IN   12
#define L_IN   8192
#define PER    5
#define NDIL   6
#define NFILT  30   // 6 dilations * 5 filters (per kernel size)
#define NFEAT  180  // 3 ks * 30 filters * 2 stats
#define NCHUNK 4
#define CHUNK  (L_IN / NCHUNK)   // 2048
#define TL     512               // positions per tile
#define EPSV   1e-5f

// ws float layout: [0, WF_OFF) partials, [WF_OFF, ..) fused weight table
#define WF_OFF (3 * N_SAMP * NCHUNK * NFILT * 2)   // 368640 floats
#define WF_SZ  (NDIL * C_IN * 11 * 16)             // 12672 floats

// ---------------------------------------------------------------------------
// Fused weight table: Wf[j][c][t5][s], t5 = tap offset + 5 (0..10),
// s: 0..4 = K7 filters, 5..9 = K9, 10..14 = K11, 15 = pad. Zero outside the
// kernel's tap range, so union-tap iteration needs no masking of loads.
// ---------------------------------------------------------------------------
__global__ __launch_bounds__(256)
void build_wf(const float* __restrict__ W7, const float* __restrict__ W9,
              const float* __restrict__ W11, float* __restrict__ wf)
{
    const int i = blockIdx.x * 256 + threadIdx.x;
    if (i >= WF_SZ) return;
    const int s  = i & 15;
    const int t5 = (i >> 4) % 11;
    const int c  = (i / (16 * 11)) % C_IN;
    const int j  = i / (16 * 11 * C_IN);
    const int t  = t5 - 5;
    float v = 0.0f;
    if (s < 5) {
        if (t >= -3 && t <= 3) v = W7[((j * PER + s) * C_IN + c) * 7 + (t + 3)];
    } else if (s < 10) {
        if (t >= -4 && t <= 4) v = W9[((j * PER + s - 5) * C_IN + c) * 9 + (t + 4)];
    } else if (s < 15) {
        v = W11[((j * PER + s - 10) * C_IN + c) * 11 + (t + 5)];
    }
    wf[i] = v;
}

// ---------------------------------------------------------------------------
// Conv kernel: one (sample, L-chunk) per block, ONE dilation, ALL 3 kernel
// sizes (15 filters). Tap offsets are nested (K7 c -3..3, K9 -4..4, K11
// -5..5), so each LDS x read feeds up to 15 filters -> ~12.3 FMA per x elem.
// 256 threads, 2 adjacent positions each.
// ---------------------------------------------------------------------------
template <int D>
__global__
__attribute__((amdgpu_flat_work_group_size(256, 256)))
__attribute__((amdgpu_waves_per_eu(4, 4)))
void rocket_conv(const float* __restrict__ x,
                 const float* __restrict__ b7,
                 const float* __restrict__ b9,
                 const float* __restrict__ b11,
                 const float* __restrict__ wfAll,
                 float* __restrict__ ws, int J)
{
    constexpr int HALO = 5 * D;
    constexpr int LW   = TL + 2 * HALO;

    __shared__ float xs[C_IN][LW];

    const int ch  = blockIdx.x;
    const int n   = blockIdx.y;
    const int tid = threadIdx.x;
    const float* __restrict__ xrow = x + (size_t)n * C_IN * L_IN;
    const float* __restrict__ wfd  = wfAll + J * (C_IN * 11 * 16);

    // biases (wave-uniform -> scalar regs)
    float bb[3][PER];
#pragma unroll
    for (int f = 0; f < PER; ++f) {
        bb[0][f] = b7[J * PER + f];
        bb[1][f] = b9[J * PER + f];
        bb[2][f] = b11[J * PER + f];
    }

    float cnt[15], mx[15];
#pragma unroll
    for (int g = 0; g < 15; ++g) { cnt[g] = 0.0f; mx[g] = -INFINITY; }

    const int c0 = ch * CHUNK;
#pragma unroll 1
    for (int t0 = c0; t0 < c0 + CHUNK; t0 += TL) {
        __syncthreads();
        // ---- stage x tile (+halo, zero-padded at sequence ends) ----
#pragma unroll 1
        for (int c = 0; c < C_IN; ++c) {
#pragma unroll 1
            for (int off = tid; off < LW; off += 256) {
                int g = t0 - HALO + off;
                xs[c][off] = ((unsigned)g < (unsigned)L_IN) ? xrow[c * L_IN + g]
                                                            : 0.0f;
            }
        }
        __syncthreads();

        const int li = HALO + 2 * tid;   // first of 2 adjacent positions

        float a[3][PER][2];
#pragma unroll
        for (int ks = 0; ks < 3; ++ks)
#pragma unroll
            for (int f = 0; f < PER; ++f) {
                a[ks][f][0] = bb[ks][f];
                a[ks][f][1] = bb[ks][f];
            }

#pragma unroll 1
        for (int c = 0; c < C_IN; ++c) {
            const float* __restrict__ xc    = &xs[c][li];
            const float* __restrict__ wrowc = wfd + c * (11 * 16);
#pragma unroll
            for (int t = -5; t <= 5; ++t) {
                const float* __restrict__ wrow = wrowc + (t + 5) * 16;
                float x0, x1;
                if (D == 1) {            // odd offsets: scalar reads (CSE'd)
                    x0 = xc[t];
                    x1 = xc[t + 1];
                } else {                  // 8B-aligned pair
                    const float2 xv = *(const float2*)(xc + t * D);
                    x0 = xv.x; x1 = xv.y;
                }
                if (t >= -3 && t <= 3) {
#pragma unroll
                    for (int f = 0; f < PER; ++f) {
                        const float w = wrow[f];
                        a[0][f][0] = fmaf(w, x0, a[0][f][0]);
                        a[0][f][1] = fmaf(w, x1, a[0][f][1]);
                    }
                }
                if (t >= -4 && t <= 4) {
#pragma unroll
                    for (int f = 0; f < PER; ++f) {
                        const float w = wrow[5 + f];
                        a[1][f][0] = fmaf(w, x0, a[1][f][0]);
                        a[1][f][1] = fmaf(w, x1, a[1][f][1]);
                    }
                }
#pragma unroll
                for (int f = 0; f < PER; ++f) {
                    const float w = wrow[10 + f];
                    a[2][f][0] = fmaf(w, x0, a[2][f][0]);
                    a[2][f][1] = fmaf(w, x1, a[2][f][1]);
                }
            }
        }

#pragma unroll
        for (int ks = 0; ks < 3; ++ks)
#pragma unroll
            for (int f = 0; f < PER; ++f) {
                const int g = ks * PER + f;
                cnt[g] += ((a[ks][f][0] > 0.0f) ? 1.0f : 0.0f)
                        + ((a[ks][f][1] > 0.0f) ? 1.0f : 0.0f);
                mx[g]   = fmaxf(mx[g], fmaxf(a[ks][f][0], a[ks][f][1]));
            }
    }

    // ---- block reduction: 256 threads -> 15 (cnt sum, max) ----
    __syncthreads();                      // xs dead; alias reduction scratch
    float* redc = &xs[0][0];              // [4][15]
    float* redm = &xs[0][0] + 4 * 15;     // [4][15]

    const int lane = tid & 63;
    const int wv   = tid >> 6;
#pragma unroll
    for (int g = 0; g < 15; ++g) {
        float cv = cnt[g], mv = mx[g];
#pragma unroll
        for (int off = 32; off; off >>= 1) {
            cv += __shfl_xor(cv, off);
            mv  = fmaxf(mv, __shfl_xor(mv, off));
        }
        if (lane == 0) { redc[wv * 15 + g] = cv; redm[wv * 15 + g] = mv; }
    }
    __syncthreads();

    if (tid < 15) {
        float cv = 0.0f, mv = -INFINITY;
#pragma unroll
        for (int w = 0; w < 4; ++w) {
            cv += redc[w * 15 + tid];
            mv  = fmaxf(mv, redm[w * 15 + tid]);
        }
        const int ks = tid / PER;
        const int f  = tid % PER;
        const int g_global = J * PER + f;      // filter index within this ks
        const size_t base =
            ((((size_t)ks * N_SAMP + n) * NCHUNK + ch) * NFILT + g_global) * 2;
        ws[base]     = cv;   // raw positive count for this chunk
        ws[base + 1] = mv;   // chunk max
    }
}

// ---------------------------------------------------------------------------
// Kernel 3: reduce chunks -> feature value, then per-feature batch norm.
// Grid: 180 blocks (one per feature), 512 threads (one per sample).
// ---------------------------------------------------------------------------
__global__ __launch_bounds__(512)
void rocket_finish(const float* __restrict__ ws, float* __restrict__ out)
{
    const int i = blockIdx.x;    // feature index 0..179
    const int t = threadIdx.x;   // sample

    const int ks = i / 60;
    const int r  = i % 60;       // j*10 + f*2 + m
    const int g  = r >> 1;       // j*5 + f
    const int m  = r & 1;        // 0 = ppv, 1 = max

    const size_t base =
        ((((size_t)ks * N_SAMP + t) * NCHUNK) * NFILT + g) * 2 + m;

    float v;
    if (m) {
        v = -INFINITY;
#pragma unroll
        for (int c = 0; c < NCHUNK; ++c)
            v = fmaxf(v, ws[base + (size_t)c * NFILT * 2]);
    } else {
        v = 0.0f;
#pragma unroll
        for (int c = 0; c < NCHUNK; ++c)
            v += ws[base + (size_t)c * NFILT * 2];
        v *= (1.0f / (float)L_IN);
    }

    // ---- mean / var over 512 samples ----
    float s  = v;
    float sq = v * v;
#pragma unroll
    for (int off = 32; off; off >>= 1) {
        s  += __shfl_xor(s, off);
        sq += __shfl_xor(sq, off);
    }

    __shared__ float ss[8], sqq[8];
    const int lane = t & 63;
    const int wv   = t >> 6;
    if (lane == 0) { ss[wv] = s; sqq[wv] = sq; }
    __syncthreads();
    if (t == 0) {
        float S = 0.0f, Q = 0.0f;
#pragma unroll
        for (int w = 0; w < 8; ++w) { S += ss[w]; Q += sqq[w]; }
        ss[0] = S; sqq[0] = Q;
    }
    __syncthreads();

    const float mean = ss[0] * (1.0f / (float)N_SAMP);
    const float var  = sqq[0] * (1.0f / (float)N_SAMP) - mean * mean;
    out[t * NFEAT + i] = (v - mean) / sqrtf(var + EPSV);
}

// ---------------------------------------------------------------------------
extern "C" void kernel_launch(void* const* d_in, const int* in_sizes, int n_in,
                              void* d_out, int out_size, void* d_ws, size_t ws_size,
                              hipStream_t stream)
{
    const float* x   = (const float*)d_in[0];
    const float* W7  = (const float*)d_in[1];
    const float* b7  = (const float*)d_in[2];
    const float* W9  = (const float*)d_in[3];
    const float* b9  = (const float*)d_in[4];
    const float* W11 = (const float*)d_in[5];
    const float* b11 = (const float*)d_in[6];
    float* out = (float*)d_out;
    float* ws  = (float*)d_ws;                 // 1.47 MB partials + 50 KB Wf
    float* wf  = ws + WF_OFF;

    build_wf<<<(WF_SZ + 255) / 256, 256, 0, stream>>>(W7, W9, W11, wf);

    dim3 grid(NCHUNK, N_SAMP);
    rocket_conv< 1><<<grid, 256, 0, stream>>>(x, b7, b9, b11, wf, ws, 0);
    rocket_conv< 2><<<grid, 256, 0, stream>>>(x, b7, b9, b11, wf, ws, 1);
    rocket_conv< 4><<<grid, 256, 0, stream>>>(x, b7, b9, b11, wf, ws, 2);
    rocket_conv< 8><<<grid, 256, 0, stream>>>(x, b7, b9, b11, wf, ws, 3);
    rocket_conv<16><<<grid, 256, 0, stream>>>(x, b7, b9, b11, wf, ws, 4);
    rocket_conv<32><<<grid, 256, 0, stream>>>(x, b7, b9, b11, wf, ws, 5);

    rocket_finish<<<NFEAT, 512, 0, stream>>>(ws, out);
}

// Round 6
// 594.975 us; speedup vs baseline: 2.7083x; 2.2182x over previous
//
#include <hip/hip_runtime.h>
#include <math.h>

#define N_SAMP 512
#define C_IN   12
#define L_IN   8192
#define PER    5
#define NDIL   6
#define NFILT  30
#define NFEAT  180
#define NCHUNK 4
#define CHUNK  (L_IN / NCHUNK)   // 2048
#define EPSV   1e-5f

#define HALO   160               // 5 * max dilation(32)
#define TLC    256               // positions per stage tile
#define LWC    (TLC + 2*HALO)    // 576 rows
#define ROWS   24                // shorts per LDS row (48 B = 12-bank stride)

// ws float layout: [0, WF_OFF) partials; then wb_hi, wb_lo (ushort), bias
#define WF_OFF (3 * N_SAMP * NCHUNK * NFILT * 2)   // 368640 floats
#define WB_USHORTS (NDIL * 6 * 64 * 8)             // 18432 per table

typedef __attribute__((ext_vector_type(8))) short s16x8;
typedef __attribute__((ext_vector_type(4))) float f32x4;

__device__ __forceinline__ unsigned short f2bf(float f) {
    unsigned u = __builtin_bit_cast(unsigned, f);
    unsigned r = (u + 0x7FFFu + ((u >> 16) & 1u)) >> 16;
    return (unsigned short)r;
}
__device__ __forceinline__ float bf2f(unsigned short h) {
    unsigned u = ((unsigned)h) << 16;
    return __builtin_bit_cast(float, u);
}

// ---------------------------------------------------------------------------
// Build hi/lo B-fragment tables in MFMA lane layout + bias table.
// K-step layout: k = tpair*16 + c (c 0..15, c>=12 zero). Step s<5 taps
// (2s, 2s+1); step 5 = tap 10 (g1=1 duplicate zero-weighted).
// ---------------------------------------------------------------------------
__global__ __launch_bounds__(256)
void build_wb(const float* __restrict__ W7, const float* __restrict__ W9,
              const float* __restrict__ W11, const float* __restrict__ b7,
              const float* __restrict__ b9, const float* __restrict__ b11,
              unsigned short* __restrict__ wbh, unsigned short* __restrict__ wbl,
              float* __restrict__ bias_tab)
{
    const int t = blockIdx.x * 256 + threadIdx.x;
    if (t < 2304) {                       // 6 dil * 6 steps * 64 lanes
        const int jj   = t / 384;
        const int rem  = t % 384;
        const int step = rem / 64;
        const int lane = rem % 64;
        const int col  = lane & 15;
        const int gq   = lane >> 4;
        const int chalf = gq & 1, g1 = gq >> 1;
        const int tap  = (step < 5) ? (2 * step + g1) : 10;
        const bool dup0 = (step == 5 && g1 == 1);
#pragma unroll
        for (int e = 0; e < 8; ++e) {
            const int c = chalf * 8 + e;
            float v = 0.0f;
            if (!dup0 && c < 12 && col < 15) {
                const int toff = tap - 5;
                if (col < 5) {
                    if (toff >= -3 && toff <= 3)
                        v = W7[((jj * 5 + col) * 12 + c) * 7 + toff + 3];
                } else if (col < 10) {
                    if (toff >= -4 && toff <= 4)
                        v = W9[((jj * 5 + col - 5) * 12 + c) * 9 + toff + 4];
                } else {
                    v = W11[((jj * 5 + col - 10) * 12 + c) * 11 + toff + 5];
                }
            }
            const unsigned short h = f2bf(v);
            const unsigned short l = f2bf(v - bf2f(h));
            wbh[(size_t)t * 8 + e] = h;
            wbl[(size_t)t * 8 + e] = l;
        }
    } else if (t < 2400) {
        const int i = t - 2304;
        const int j = i / 16, s = i % 16;
        float b = 0.0f;
        if (s < 5)       b = b7 [j * 5 + s];
        else if (s < 10) b = b9 [j * 5 + s - 5];
        else if (s < 15) b = b11[j * 5 + s - 10];
        bias_tab[j * 16 + s] = b;
    }
}

// ---------------------------------------------------------------------------
// MFMA conv with 3-term bf16 precision split:
//   out = A_hi*B_hi + A_hi*B_lo + A_lo*B_hi   (error ~ 2^-18 relative)
// One (sample, 2048-chunk) per block, all 6 dilations, all 3 kernel sizes.
// x staged per tile as TWO transposed bf16 tiles (hi, lo), 48B row stride.
// ---------------------------------------------------------------------------
__global__ __launch_bounds__(256)
void rocket_conv_mfma(const float* __restrict__ x,
                      const unsigned short* __restrict__ wbh,
                      const unsigned short* __restrict__ wbl,
                      const float* __restrict__ bias_tab,
                      float* __restrict__ ws)
{
    __shared__ __align__(16) short xhi[LWC * ROWS];   // 27648 B
    __shared__ __align__(16) short xlo[LWC * ROWS];   // 27648 B

    const int ch  = blockIdx.x;
    const int n   = blockIdx.y;
    const int tid = threadIdx.x;
    const int lane = tid & 63, wv = tid >> 6;
    const int row_l = lane & 15, gq = lane >> 4;
    const int chalf = gq & 1,  g1 = gq >> 1;
    const float* __restrict__ xrow = x + (size_t)n * C_IN * L_IN;

    float biasv[NDIL];
#pragma unroll
    for (int j = 0; j < NDIL; ++j) biasv[j] = bias_tab[j * 16 + row_l];

    float cnt[NDIL], mx[NDIL];
#pragma unroll
    for (int j = 0; j < NDIL; ++j) { cnt[j] = 0.0f; mx[j] = -INFINITY; }

    const int c0 = ch * CHUNK;
#pragma unroll 1
    for (int st = 0; st < CHUNK / TLC; ++st) {
        const int t0 = c0 + st * TLC;
        __syncthreads();
        // ---- stage transposed bf16 hi/lo tiles ----
#pragma unroll 1
        for (int r = tid; r < LWC; r += 256) {
            const int g = t0 - HALO + r;
            float v[12];
#pragma unroll
            for (int c = 0; c < 12; ++c)
                v[c] = ((unsigned)g < (unsigned)L_IN) ? xrow[c * L_IN + g] : 0.0f;
            s16x8 hlo, hhi, llo, lhi;
#pragma unroll
            for (int c = 0; c < 8; ++c) {
                const unsigned short h = f2bf(v[c]);
                hlo[c] = (short)h;
                llo[c] = (short)f2bf(v[c] - bf2f(h));
            }
#pragma unroll
            for (int c = 0; c < 4; ++c) {
                const unsigned short h = f2bf(v[8 + c]);
                hhi[c] = (short)h;
                lhi[c] = (short)f2bf(v[8 + c] - bf2f(h));
            }
#pragma unroll
            for (int c = 4; c < 8; ++c) { hhi[c] = 0; lhi[c] = 0; }
            *(s16x8*)&xhi[r * ROWS]     = hlo;
            *(s16x8*)&xhi[r * ROWS + 8] = hhi;
            *(s16x8*)&xlo[r * ROWS]     = llo;
            *(s16x8*)&xlo[r * ROWS + 8] = lhi;
        }
        __syncthreads();

        // ---- compute: 6 dilations x 4 pos-tiles/wave x (12 reads, 18 MFMA)
#pragma unroll
        for (int j = 0; j < NDIL; ++j) {
            const int d = 1 << j;
            s16x8 bh[6], bl[6];
#pragma unroll
            for (int s = 0; s < 6; ++s) {
                bh[s] = *(const s16x8*)(wbh + ((size_t)(j * 6 + s) * 64 + lane) * 8);
                bl[s] = *(const s16x8*)(wbl + ((size_t)(j * 6 + s) * 64 + lane) * 8);
            }
            const int baseD = (HALO + row_l + (g1 - 5) * d) * ROWS + chalf * 8;
            const int baseE = (HALO + row_l + 5 * d) * ROWS + chalf * 8;
            const float bj = biasv[j];
#pragma unroll
            for (int tile = 0; tile < 4; ++tile) {
                const int pb = (wv * 64 + tile * 16) * ROWS;
                const short* pDh = &xhi[baseD + pb];
                const short* pEh = &xhi[baseE + pb];
                const short* pDl = &xlo[baseD + pb];
                const short* pEl = &xlo[baseE + pb];
                s16x8 a0 = *(const s16x8*)(pDh);
                s16x8 a1 = *(const s16x8*)(pDh + 48 * d);
                s16x8 a2 = *(const s16x8*)(pDh + 96 * d);
                s16x8 a3 = *(const s16x8*)(pDh + 144 * d);
                s16x8 a4 = *(const s16x8*)(pDh + 192 * d);
                s16x8 a5 = *(const s16x8*)(pEh);
                s16x8 c0r = *(const s16x8*)(pDl);
                s16x8 c1 = *(const s16x8*)(pDl + 48 * d);
                s16x8 c2 = *(const s16x8*)(pDl + 96 * d);
                s16x8 c3 = *(const s16x8*)(pDl + 144 * d);
                s16x8 c4 = *(const s16x8*)(pDl + 192 * d);
                s16x8 c5 = *(const s16x8*)(pEl);
                f32x4 acc = {bj, bj, bj, bj};
                // term 1: A_hi * B_hi
                acc = __builtin_amdgcn_mfma_f32_16x16x32_bf16(a0, bh[0], acc, 0, 0, 0);
                acc = __builtin_amdgcn_mfma_f32_16x16x32_bf16(a1, bh[1], acc, 0, 0, 0);
                acc = __builtin_amdgcn_mfma_f32_16x16x32_bf16(a2, bh[2], acc, 0, 0, 0);
                acc = __builtin_amdgcn_mfma_f32_16x16x32_bf16(a3, bh[3], acc, 0, 0, 0);
                acc = __builtin_amdgcn_mfma_f32_16x16x32_bf16(a4, bh[4], acc, 0, 0, 0);
                acc = __builtin_amdgcn_mfma_f32_16x16x32_bf16(a5, bh[5], acc, 0, 0, 0);
                // term 2: A_hi * B_lo (reuse A registers)
                acc = __builtin_amdgcn_mfma_f32_16x16x32_bf16(a0, bl[0], acc, 0, 0, 0);
                acc = __builtin_amdgcn_mfma_f32_16x16x32_bf16(a1, bl[1], acc, 0, 0, 0);
                acc = __builtin_amdgcn_mfma_f32_16x16x32_bf16(a2, bl[2], acc, 0, 0, 0);
                acc = __builtin_amdgcn_mfma_f32_16x16x32_bf16(a3, bl[3], acc, 0, 0, 0);
                acc = __builtin_amdgcn_mfma_f32_16x16x32_bf16(a4, bl[4], acc, 0, 0, 0);
                acc = __builtin_amdgcn_mfma_f32_16x16x32_bf16(a5, bl[5], acc, 0, 0, 0);
                // term 3: A_lo * B_hi
                acc = __builtin_amdgcn_mfma_f32_16x16x32_bf16(c0r, bh[0], acc, 0, 0, 0);
                acc = __builtin_amdgcn_mfma_f32_16x16x32_bf16(c1, bh[1], acc, 0, 0, 0);
                acc = __builtin_amdgcn_mfma_f32_16x16x32_bf16(c2, bh[2], acc, 0, 0, 0);
                acc = __builtin_amdgcn_mfma_f32_16x16x32_bf16(c3, bh[3], acc, 0, 0, 0);
                acc = __builtin_amdgcn_mfma_f32_16x16x32_bf16(c4, bh[4], acc, 0, 0, 0);
                acc = __builtin_amdgcn_mfma_f32_16x16x32_bf16(c5, bh[5], acc, 0, 0, 0);
#pragma unroll
                for (int r4 = 0; r4 < 4; ++r4) {
                    cnt[j] += (acc[r4] > 0.0f) ? 1.0f : 0.0f;
                    mx[j]   = fmaxf(mx[j], acc[r4]);
                }
            }
        }
    }

    // ---- reduce: lanes {s, s+16, s+32, s+48} hold same filter col s ----
    __syncthreads();                       // tiles dead; alias scratch
    float* redc = (float*)xhi;             // [4][6][16]
    float* redm = redc + 384;
#pragma unroll
    for (int j = 0; j < NDIL; ++j) {
        float c = cnt[j], m = mx[j];
        c += __shfl_xor(c, 16);  m = fmaxf(m, __shfl_xor(m, 16));
        c += __shfl_xor(c, 32);  m = fmaxf(m, __shfl_xor(m, 32));
        if (lane < 16) {
            redc[(wv * 6 + j) * 16 + lane] = c;
            redm[(wv * 6 + j) * 16 + lane] = m;
        }
    }
    __syncthreads();

    if (tid < 96) {
        const int jj = tid >> 4, s = tid & 15;
        if (s < 15) {
            float c = 0.0f, m = -INFINITY;
#pragma unroll
            for (int w = 0; w < 4; ++w) {
                c += redc[(w * 6 + jj) * 16 + s];
                m  = fmaxf(m, redm[(w * 6 + jj) * 16 + s]);
            }
            const int ks = s / 5, f = s % 5;
            const int gg = jj * 5 + f;
            const size_t base =
                ((((size_t)ks * N_SAMP + n) * NCHUNK + ch) * NFILT + gg) * 2;
            ws[base]     = c;
            ws[base + 1] = m;
        }
    }
}

// ---------------------------------------------------------------------------
// Reduce chunks -> feature value, then per-feature batch norm.
// ---------------------------------------------------------------------------
__global__ __launch_bounds__(512)
void rocket_finish(const float* __restrict__ ws, float* __restrict__ out)
{
    const int i = blockIdx.x;
    const int t = threadIdx.x;

    const int ks = i / 60;
    const int r  = i % 60;
    const int g  = r >> 1;
    const int m  = r & 1;

    const size_t base =
        ((((size_t)ks * N_SAMP + t) * NCHUNK) * NFILT + g) * 2 + m;

    float v;
    if (m) {
        v = -INFINITY;
#pragma unroll
        for (int c = 0; c < NCHUNK; ++c)
            v = fmaxf(v, ws[base + (size_t)c * NFILT * 2]);
    } else {
        v = 0.0f;
#pragma unroll
        for (int c = 0; c < NCHUNK; ++c)
            v += ws[base + (size_t)c * NFILT * 2];
        v *= (1.0f / (float)L_IN);
    }

    float s  = v;
    float sq = v * v;
#pragma unroll
    for (int off = 32; off; off >>= 1) {
        s  += __shfl_xor(s, off);
        sq += __shfl_xor(sq, off);
    }

    __shared__ float ss[8], sqq[8];
    const int lane = t & 63;
    const int wv   = t >> 6;
    if (lane == 0) { ss[wv] = s; sqq[wv] = sq; }
    __syncthreads();
    if (t == 0) {
        float S = 0.0f, Q = 0.0f;
#pragma unroll
        for (int w = 0; w < 8; ++w) { S += ss[w]; Q += sqq[w]; }
        ss[0] = S; sqq[0] = Q;
    }
    __syncthreads();

    const float mean = ss[0] * (1.0f / (float)N_SAMP);
    const float var  = sqq[0] * (1.0f / (float)N_SAMP) - mean * mean;
    out[t * NFEAT + i] = (v - mean) / sqrtf(var + EPSV);
}

// ---------------------------------------------------------------------------
extern "C" void kernel_launch(void* const* d_in, const int* in_sizes, int n_in,
                              void* d_out, int out_size, void* d_ws, size_t ws_size,
                              hipStream_t stream)
{
    const float* x   = (const float*)d_in[0];
    const float* W7  = (const float*)d_in[1];
    const float* b7  = (const float*)d_in[2];
    const float* W9  = (const float*)d_in[3];
    const float* b9  = (const float*)d_in[4];
    const float* W11 = (const float*)d_in[5];
    const float* b11 = (const float*)d_in[6];
    float* out = (float*)d_out;
    float* ws  = (float*)d_ws;
    unsigned short* wbh = (unsigned short*)(ws + WF_OFF);
    unsigned short* wbl = wbh + WB_USHORTS;
    float* bias_tab = (float*)(wbl + WB_USHORTS);

    build_wb<<<10, 256, 0, stream>>>(W7, W9, W11, b7, b9, b11, wbh, wbl, bias_tab);

    dim3 grid(NCHUNK, N_SAMP);
    rocket_conv_mfma<<<grid, 256, 0, stream>>>(x, wbh, wbl, bias_tab, ws);

    rocket_finish<<<NFEAT, 512, 0, stream>>>(ws, out);
}